// Round 2
// baseline (20.763 us; speedup 1.0000x reference)
//
#include <hip/hip_runtime.h>
#include <hip/hip_bf16.h>

constexpr int HS = 4;   // hedge slots
constexpr int NS = 64;  // neighbor samples == wavefront size
constexpr int T  = 32;  // n_types == output dim
constexpr int E  = 64;  // node embedding width
constexpr int WAVES = 4; // rows per 256-thread block

// 4 waves per block, one batch row per wave. No atomics, no __syncthreads:
// histogram is built from wave-uniform ballots (lives in SGPRs), LDS is
// per-wave and accessed wave-synchronously.
__global__ __launch_bounds__(256)
void polyhype_kernel(const int*   __restrict__ neighbors,      // [B, HS]
                     const int*   __restrict__ train_hedges,   // [B]
                     const int*   __restrict__ labels,         // [B]
                     const int*   __restrict__ neighborhedges, // [N_NODES, NS]
                     const int*   __restrict__ hedgetypes,     // [N_HEDGES]
                     const int*   __restrict__ nodeEmb,        // [N_NODES, E]
                     const float* __restrict__ tf,             // [T, T]
                     const float* __restrict__ W1,             // [T, T]
                     const float* __restrict__ b1,             // [T]
                     const float* __restrict__ W2,             // [E, T]
                     const float* __restrict__ b2,             // [T]
                     float*       __restrict__ out,            // scores|sig|emb
                     int B)
{
    const int wid  = threadIdx.x >> 6;   // wave within block
    const int lane = threadIdx.x & 63;
    const int b    = blockIdx.x * WAVES + wid;
    if (b >= B) return;

    __shared__ float emb_s[WAVES][E];    // per-wave mean node embedding
    __shared__ float agg_s[WAVES][T];    // per-wave agg vector

    const int th = train_hedges[b];

    // --- gather phase: launch all 4 chains at once ---
    const int4 nd = ((const int4*)neighbors)[b];       // 4 node ids, one dwordx4
    int node[HS] = { nd.x, nd.y, nd.z, nd.w };

    int edge[HS];
    #pragma unroll
    for (int h = 0; h < HS; ++h)
        edge[h] = neighborhedges[(size_t)node[h] * NS + lane];   // coalesced 256B rows

    int ty[HS];
    #pragma unroll
    for (int h = 0; h < HS; ++h)
        ty[h] = hedgetypes[edge[h]];                             // random 4B (L2-resident table)

    float eacc = 0.f;
    #pragma unroll
    for (int h = 0; h < HS; ++h)
        eacc += (float)nodeEmb[(size_t)node[h] * E + lane];      // coalesced 256B rows
    emb_s[wid][lane] = eacc * (1.0f / HS);

    // --- masks (wave-uniform, SGPR) ---
    unsigned long long mm[HS];
    float den[HS];
    #pragma unroll
    for (int h = 0; h < HS; ++h) {
        mm[h]  = __ballot(edge[h] != th);
        den[h] = fmaxf((float)__popcll(mm[h]), 1.0f);
    }

    // --- ballot histogram -> dot with tf column t (all lanes compute; halves dup) ---
    const int t = lane & 31;
    float agg = 0.f;
    #pragma unroll
    for (int h = 0; h < HS; ++h) {
        float s = 0.f;
        #pragma unroll 8
        for (int k = 0; k < T; ++k) {
            const float cnt = (float)__popcll(__ballot(ty[h] == k) & mm[h]); // SGPR count
            s += cnt * tf[k * T + t];                                        // L1-hit row
        }
        agg += s / den[h];
    }
    agg = agg * (1.0f / HS) + tf[labels[b] * T + t];   // + self vector
    if (lane < T) agg_s[wid][t] = agg;

    __builtin_amdgcn_wave_barrier();   // compiler fence; wave-synchronous LDS

    // --- tiny matvecs ---
    float result;
    if (lane < T) {
        float v = b1[t];
        #pragma unroll 8
        for (int u = 0; u < T; ++u)
            v += agg_s[wid][u] * W1[u * T + t];
        result = v;
    } else {
        float v = b2[t];
        #pragma unroll 8
        for (int e = 0; e < E; ++e)
            v += emb_s[wid][e] * W2[e * T + t];
        result = v;
    }

    // --- outputs: scores [B*T] | sigmoid [B*T] | embedding [B*2T] ---
    float* scores = out;
    float* sig    = out + (size_t)B * T;
    float* emb    = out + (size_t)2 * B * T;
    if (lane < T) {
        const float s = result;
        scores[b * T + t] = s;
        sig[b * T + t]    = 1.0f / (1.0f + expf(-s));
        emb[(size_t)b * 2 * T + t] = s;
    } else {
        emb[(size_t)b * 2 * T + T + t] = result;
    }
}

extern "C" void kernel_launch(void* const* d_in, const int* in_sizes, int n_in,
                              void* d_out, int out_size, void* d_ws, size_t ws_size,
                              hipStream_t stream) {
    const int*   neighbors      = (const int*)  d_in[0];
    const int*   train_hedges   = (const int*)  d_in[1];
    const int*   labels         = (const int*)  d_in[2];
    const int*   neighborhedges = (const int*)  d_in[3];
    const int*   hedgetypes     = (const int*)  d_in[4];
    const int*   nodeEmb        = (const int*)  d_in[5];
    const float* tf             = (const float*)d_in[6];
    const float* W1             = (const float*)d_in[7];
    const float* b1             = (const float*)d_in[8];
    const float* W2             = (const float*)d_in[9];
    const float* b2             = (const float*)d_in[10];
    float*       out            = (float*)      d_out;

    const int B = in_sizes[1];   // train_hedges is [B]

    const int grid = (B + WAVES - 1) / WAVES;
    polyhype_kernel<<<grid, 256, 0, stream>>>(
        neighbors, train_hedges, labels, neighborhedges, hedgetypes, nodeEmb,
        tf, W1, b1, W2, b2, out, B);
}

// Round 3
// 17.040 us; speedup vs baseline: 1.2185x; 1.2185x over previous
//
#include <hip/hip_runtime.h>
#include <hip/hip_bf16.h>

constexpr int HS = 4;   // hedge slots
constexpr int NS = 64;  // neighbor samples == wavefront size
constexpr int T  = 32;  // n_types == output dim
constexpr int E  = 64;  // node embedding width

// One block (4 waves) per batch row; wave h owns hedge slot h.
// Shorter per-wave dependent chains + 4x wave count for latency hiding.
__global__ __launch_bounds__(256)
void polyhype_kernel(const int*   __restrict__ neighbors,      // [B, HS]
                     const int*   __restrict__ train_hedges,   // [B]
                     const int*   __restrict__ labels,         // [B]
                     const int*   __restrict__ neighborhedges, // [N_NODES, NS]
                     const int*   __restrict__ hedgetypes,     // [N_HEDGES]
                     const int*   __restrict__ nodeEmb,        // [N_NODES, E]
                     const float* __restrict__ tf,             // [T, T]
                     const float* __restrict__ W1,             // [T, T]
                     const float* __restrict__ b1,             // [T]
                     const float* __restrict__ W2,             // [E, T]
                     const float* __restrict__ b2,             // [T]
                     float*       __restrict__ out,            // scores|sig|emb
                     int B)
{
    const int b    = blockIdx.x;
    const int wid  = threadIdx.x >> 6;   // hedge slot h
    const int lane = threadIdx.x & 63;
    const int t    = lane & 31;

    __shared__ float aggp[HS][T];   // per-slot masked-mean type vector
    __shared__ float embp[HS][E];   // per-slot nodeEmb row
    __shared__ float emb_mean[E];
    __shared__ float agg_full[T];

    const int th   = train_hedges[b];
    const int node = neighbors[b * HS + wid];                     // wave-uniform

    // gather chain for this slot
    const int edge = neighborhedges[(size_t)node * NS + lane];    // coalesced 256B row
    const int ty   = hedgetypes[edge];                            // random 4B (L2)
    embp[wid][lane] = (float)nodeEmb[(size_t)node * E + lane];    // coalesced 256B row

    const unsigned long long mm = __ballot(edge != th);
    const float rden = 1.0f / fmaxf((float)__popcll(mm), 1.0f);

    // ballot histogram -> dot with tf column t (32 iters; halves duplicate)
    float s = 0.f;
    #pragma unroll
    for (int k = 0; k < T; ++k) {
        const float cnt = (float)__popcll(__ballot(ty == k) & mm);
        s += cnt * tf[k * T + t];
    }
    if (lane < T) aggp[wid][t] = s * rden;

    __syncthreads();

    if (wid == 0) {
        // agg vector + W1 matvec + scores/sigmoid/emb-low outputs
        if (lane < T) {
            float agg = (aggp[0][t] + aggp[1][t] + aggp[2][t] + aggp[3][t]) * 0.25f
                      + tf[labels[b] * T + t];
            agg_full[t] = agg;
        }
        __builtin_amdgcn_wave_barrier();
        if (lane < T) {
            float v = b1[t];
            #pragma unroll 8
            for (int u = 0; u < T; ++u)
                v += agg_full[u] * W1[u * T + t];
            float* scores = out;
            float* sig    = out + (size_t)B * T;
            float* emb    = out + (size_t)2 * B * T;
            scores[b * T + t] = v;
            sig[b * T + t]    = 1.0f / (1.0f + __expf(-v));
            emb[(size_t)b * 2 * T + t] = v;
        }
    } else if (wid == 1) {
        // mean nodeEmb (64 lanes) then W2 matvec (32 lanes)
        emb_mean[lane] = (embp[0][lane] + embp[1][lane] + embp[2][lane] + embp[3][lane]) * 0.25f;
        __builtin_amdgcn_wave_barrier();
        if (lane < T) {
            float v = b2[t];
            #pragma unroll 8
            for (int e = 0; e < E; ++e)
                v += emb_mean[e] * W2[e * T + t];
            float* emb = out + (size_t)2 * B * T;
            emb[(size_t)b * 2 * T + T + t] = v;
        }
    }
}

extern "C" void kernel_launch(void* const* d_in, const int* in_sizes, int n_in,
                              void* d_out, int out_size, void* d_ws, size_t ws_size,
                              hipStream_t stream) {
    const int*   neighbors      = (const int*)  d_in[0];
    const int*   train_hedges   = (const int*)  d_in[1];
    const int*   labels         = (const int*)  d_in[2];
    const int*   neighborhedges = (const int*)  d_in[3];
    const int*   hedgetypes     = (const int*)  d_in[4];
    const int*   nodeEmb        = (const int*)  d_in[5];
    const float* tf             = (const float*)d_in[6];
    const float* W1             = (const float*)d_in[7];
    const float* b1             = (const float*)d_in[8];
    const float* W2             = (const float*)d_in[9];
    const float* b2             = (const float*)d_in[10];
    float*       out            = (float*)      d_out;

    const int B = in_sizes[1];   // train_hedges is [B]

    polyhype_kernel<<<B, 256, 0, stream>>>(
        neighbors, train_hedges, labels, neighborhedges, hedgetypes, nodeEmb,
        tf, W1, b1, W2, b2, out, B);
}

// Round 4
// 17.003 us; speedup vs baseline: 1.2211x; 1.0022x over previous
//
#include <hip/hip_runtime.h>
#include <hip/hip_bf16.h>

constexpr int HS = 4;   // hedge slots
constexpr int NS = 64;  // neighbor samples == wavefront size
constexpr int T  = 32;  // n_types == output dim
constexpr int E  = 64;  // node embedding width
constexpr int RPB = 2;  // rows per block

// 2 rows per 256-thread block; wave h owns hedge slot h for BOTH rows
// (2 independent gather chains in flight per wave). Grid = B/2 = 2048 blocks
// -> one resident batch across 256 CUs. All 4 waves have post-sync work.
__global__ __launch_bounds__(256)
void polyhype_kernel(const int*   __restrict__ neighbors,      // [B, HS]
                     const int*   __restrict__ train_hedges,   // [B]
                     const int*   __restrict__ labels,         // [B]
                     const int*   __restrict__ neighborhedges, // [N_NODES, NS]
                     const int*   __restrict__ hedgetypes,     // [N_HEDGES]
                     const int*   __restrict__ nodeEmb,        // [N_NODES, E]
                     const float* __restrict__ tf,             // [T, T]
                     const float* __restrict__ W1,             // [T, T]
                     const float* __restrict__ b1,             // [T]
                     const float* __restrict__ W2,             // [E, T]
                     const float* __restrict__ b2,             // [T]
                     float*       __restrict__ out,            // scores|sig|emb
                     int B)
{
    const int wid  = threadIdx.x >> 6;   // hedge slot h
    const int lane = threadIdx.x & 63;
    const int t    = lane & 31;
    const int b0   = blockIdx.x * RPB;
    const int b1r  = b0 + 1;

    __shared__ float aggp[RPB][HS][T];   // per-row per-slot masked-mean type vec
    __shared__ float embp[RPB][HS][E];   // per-row per-slot nodeEmb row

    const int th0 = train_hedges[b0];
    const int th1 = train_hedges[b1r];
    const int n0  = neighbors[b0  * HS + wid];   // wave-uniform
    const int n1  = neighbors[b1r * HS + wid];

    // --- both gather chains issued back-to-back (ILP=2) ---
    const int e0 = neighborhedges[(size_t)n0 * NS + lane];
    const int e1 = neighborhedges[(size_t)n1 * NS + lane];
    const int t0 = hedgetypes[e0];
    const int t1 = hedgetypes[e1];
    embp[0][wid][lane] = (float)nodeEmb[(size_t)n0 * E + lane];
    embp[1][wid][lane] = (float)nodeEmb[(size_t)n1 * E + lane];

    const unsigned long long mm0 = __ballot(e0 != th0);
    const unsigned long long mm1 = __ballot(e1 != th1);
    const float rd0 = 1.0f / fmaxf((float)__popcll(mm0), 1.0f);
    const float rd1 = 1.0f / fmaxf((float)__popcll(mm1), 1.0f);

    // --- ballot histogram for both rows; tf row element shared per k ---
    float s0 = 0.f, s1 = 0.f;
    #pragma unroll
    for (int k = 0; k < T; ++k) {
        const float w  = tf[k * T + t];
        const float c0 = (float)__popcll(__ballot(t0 == k) & mm0);
        const float c1 = (float)__popcll(__ballot(t1 == k) & mm1);
        s0 += c0 * w;
        s1 += c1 * w;
    }
    if (lane < T) {
        aggp[0][wid][t] = s0 * rd0;
        aggp[1][wid][t] = s1 * rd1;
    }

    __syncthreads();

    // post-sync: wave 0 -> row0 scores, wave 1 -> row0 emb,
    //            wave 2 -> row1 scores, wave 3 -> row1 emb
    const int r  = wid >> 1;          // row index
    const int br = b0 + r;
    float* scores = out;
    float* sig    = out + (size_t)B * T;
    float* emb    = out + (size_t)2 * B * T;

    if ((wid & 1) == 0) {
        if (lane < T) {
            float agg = (aggp[r][0][t] + aggp[r][1][t] + aggp[r][2][t] + aggp[r][3][t]) * 0.25f
                      + tf[labels[br] * T + t];
            // broadcast agg across the 32 active lanes via LDS reuse
            aggp[r][0][t] = agg;
        }
        __builtin_amdgcn_wave_barrier();
        if (lane < T) {
            float v = b1[t];
            #pragma unroll 8
            for (int u = 0; u < T; ++u)
                v += aggp[r][0][u] * W1[u * T + t];
            scores[br * T + t] = v;
            sig[br * T + t]    = 1.0f / (1.0f + __expf(-v));
            emb[(size_t)br * 2 * T + t] = v;
        }
    } else {
        // mean nodeEmb across slots (64 lanes), stage, then W2 matvec (32 lanes)
        const float em = (embp[r][0][lane] + embp[r][1][lane] +
                          embp[r][2][lane] + embp[r][3][lane]) * 0.25f;
        embp[r][0][lane] = em;
        __builtin_amdgcn_wave_barrier();
        if (lane < T) {
            float v = b2[t];
            #pragma unroll 8
            for (int e = 0; e < E; ++e)
                v += embp[r][0][e] * W2[e * T + t];
            emb[(size_t)br * 2 * T + T + t] = v;
        }
    }
}

extern "C" void kernel_launch(void* const* d_in, const int* in_sizes, int n_in,
                              void* d_out, int out_size, void* d_ws, size_t ws_size,
                              hipStream_t stream) {
    const int*   neighbors      = (const int*)  d_in[0];
    const int*   train_hedges   = (const int*)  d_in[1];
    const int*   labels         = (const int*)  d_in[2];
    const int*   neighborhedges = (const int*)  d_in[3];
    const int*   hedgetypes     = (const int*)  d_in[4];
    const int*   nodeEmb        = (const int*)  d_in[5];
    const float* tf             = (const float*)d_in[6];
    const float* W1             = (const float*)d_in[7];
    const float* b1             = (const float*)d_in[8];
    const float* W2             = (const float*)d_in[9];
    const float* b2             = (const float*)d_in[10];
    float*       out            = (float*)      d_out;

    const int B = in_sizes[1];   // train_hedges is [B]

    const int grid = (B + RPB - 1) / RPB;
    polyhype_kernel<<<grid, 256, 0, stream>>>(
        neighbors, train_hedges, labels, neighborhedges, hedgetypes, nodeEmb,
        tf, W1, b1, W2, b2, out, B);
}